// Round 6
// baseline (393.584 us; speedup 1.0000x reference)
//
#include <hip/hip_runtime.h>
#include <hip/hip_bf16.h>

// B=16, C=512, H=W=64, HW=4096, NH=8, HD=64, QK_CH=64.  FP32 I/O.
// Pipeline:
//  k_wcvt : Wq|Wk|Wv -> Wcat_b16[640][512], Wo -> Wo_b16[512][512]   (ws)
//  k_proj : qkv[b][o][s] = Wcat @ x[b] + bias  (MFMA, 128x128 tile, BK=64).
//           LDS is fully bank-floor (verified by bank arithmetic):
//             Bs[s][c] bf16, 128B rows, XOR-swizzled 16B slots
//               addr = s*128B + 16*(slot ^ (s&7));  write side: thread owns
//               one s-column + 4 8-c slots (32 coalesced scalar x-loads ->
//               v_cvt_pk_bf16_f32 -> 4x ds_write_b128, 8 accesses/bank);
//             As via global_load_lds with PRE-SWIZZLED GLOBAL SOURCE
//               (rule #21: linear LDS dest, lane col = ((lane&7)^(lane>>3))*8),
//               so fragment reads use the same XOR and are conflict-free.
//           8 K-steps (2 barriers each), x prefetched one step ahead.
//  k_attn : fused scores+softmax+apply per (b,head) (see below).
//  k_out  : d_out fp32 [65536][512] = Xb16 @ Wo_b16^T + bo  (MFMA)
// ws peak: 64 MiB (Xb16) + 1.2 MiB (weights).
// d_out used as qkv scratch [0,80 MiB) until k_out fully overwrites it.

#define B_  16
#define C_  512
#define HW_ 4096
#define NO_ 640

typedef unsigned short u16;
typedef unsigned int   u32;
typedef __attribute__((ext_vector_type(8))) short bh8;   // 8 bf16 (4 VGPRs)
typedef __attribute__((ext_vector_type(4))) float f32x4; // MFMA C/D
typedef __attribute__((ext_vector_type(4))) unsigned int u32x4;

__device__ __forceinline__ float bf2f(u16 u) {
    unsigned v = ((unsigned)u) << 16;
    return __uint_as_float(v);
}
__device__ __forceinline__ u16 f2bf(float f) {
    unsigned u = __float_as_uint(f);
    unsigned r = (u + 0x7FFFu + ((u >> 16) & 1u)) >> 16;  // RNE
    return (u16)r;
}
// pack 2 f32 -> 2 bf16 (RNE), lo in low 16 bits.
__device__ __forceinline__ u32 cvtpk(float lo, float hi) {
    u32 r;
    asm("v_cvt_pk_bf16_f32 %0, %1, %2" : "=v"(r) : "v"(lo), "v"(hi));
    return r;
}

// async global->LDS, 16 B per lane; LDS dest = wave-uniform base + lane*16.
__device__ __forceinline__ void gl2lds(const u16* g, u16* l) {
    __builtin_amdgcn_global_load_lds(
        (const __attribute__((address_space(1))) unsigned int*)(const void*)g,
        (__attribute__((address_space(3))) unsigned int*)(void*)l, 16, 0, 0);
}

// ---------------- weight conversion ----------------
__global__ __launch_bounds__(256) void k_wcvt(
    const float* __restrict__ Wq, const float* __restrict__ Wk,
    const float* __restrict__ Wv, const float* __restrict__ Wo,
    u16* __restrict__ Wcat, u16* __restrict__ Wob)
{
    int idx = blockIdx.x * 256 + threadIdx.x;
    if (idx < NO_ * C_) {
        int o = idx >> 9, c = idx & 511;
        float v = (o < 64) ? Wq[o * C_ + c]
                : (o < 128) ? Wk[(o - 64) * C_ + c]
                : Wv[(size_t)(o - 128) * C_ + c];
        Wcat[idx] = f2bf(v);
    }
    int idx2 = idx - NO_ * C_;
    if (idx2 >= 0 && idx2 < C_ * C_) Wob[idx2] = f2bf(Wo[idx2]);
}

// ---------------- k_proj (MFMA): qkv[b][o][s] = Wcat @ x[b] + bias ----------------
// A = Wcat[640][512] ([m][k], bf16).  B from x[b][c][s] fp32, transposed into
// swizzled LDS per K-step.  Tile 128x128, BK=64.  grid (32 n, 5 m, 16 b).
__global__ __launch_bounds__(256) void k_proj(
    const u16* __restrict__ Wcat, const float* __restrict__ x,
    const float* __restrict__ bq, const float* __restrict__ bk,
    const float* __restrict__ bv, u16* __restrict__ qkv)
{
    __shared__ u16 As[128 * 64];    // 16 KiB, linear rows, content pre-swizzled
    __shared__ u16 Bs[128 * 64];    // 16 KiB, XOR-swizzled slots
    const int t = threadIdx.x;
    const int lane = t & 63, w = t >> 6;
    const int q = lane >> 4, ln = lane & 15;
    const int n0 = blockIdx.x * 128, m0 = blockIdx.y * 128, b = blockIdx.z;
    const int wm = (w >> 1) * 64, wn = (w & 1) * 64;
    // A staging: lane -> row rowblk+(lane>>3), slot lane&7; global col carries
    // the inverse swizzle so LDS content(row, ss) = c-slot (ss ^ (row&7)).
    const int arow = lane >> 3;
    const int aswz = ((lane & 7) ^ arow) * 8;   // u16 col offset, 16B units
    // B staging: thread owns s-column sB, slots {(t>>7) + 2k : k=0..3}.
    const int sB = t & 127;
    const int cH = (t >> 7) * 8;                // base c of first slot (u16)
    const float* xs = x + (size_t)b * C_ * HW_ + n0 + sB;

    f32x4 acc[4][4];
#pragma unroll
    for (int i = 0; i < 4; ++i)
#pragma unroll
        for (int j = 0; j < 4; ++j) acc[i][j] = (f32x4){0.f, 0.f, 0.f, 0.f};

    // prologue: first x tile (32 scalar coalesced loads: lane-consecutive s)
    float xv[32];
#pragma unroll
    for (int k = 0; k < 4; ++k)
#pragma unroll
        for (int m = 0; m < 8; ++m)
            xv[k * 8 + m] = xs[(size_t)(cH + 16 * k + m) * HW_];

    for (int kt = 0; kt < 8; ++kt) {
        const int k0 = kt * 64;
        __syncthreads();
        // stage A (async DMA, 4 rounds x 4 waves x 8 rows of 128B)
#pragma unroll
        for (int i = 0; i < 4; ++i) {
            int rowblk = (i * 4 + w) * 8;
            gl2lds(Wcat + (size_t)(m0 + rowblk + arow) * C_ + k0 + aswz,
                   &As[rowblk * 64]);
        }
        // write B: 4 swizzled b128 slots (bank floor: 8 accesses/bank/wave)
#pragma unroll
        for (int k = 0; k < 4; ++k) {
            int slot = (cH >> 3) + 2 * k;
            u32x4 o;
            o.x = cvtpk(xv[k * 8 + 0], xv[k * 8 + 1]);
            o.y = cvtpk(xv[k * 8 + 2], xv[k * 8 + 3]);
            o.z = cvtpk(xv[k * 8 + 4], xv[k * 8 + 5]);
            o.w = cvtpk(xv[k * 8 + 6], xv[k * 8 + 7]);
            *(u32x4*)&Bs[sB * 64 + ((slot ^ (sB & 7)) * 8)] = o;
        }
        __syncthreads();
        // prefetch next x tile (hides under the 32 MFMAs below)
        if (kt < 7) {
#pragma unroll
            for (int k = 0; k < 4; ++k)
#pragma unroll
                for (int m = 0; m < 8; ++m)
                    xv[k * 8 + m] = xs[(size_t)(k0 + 64 + cH + 16 * k + m) * HW_];
        }
#pragma unroll
        for (int kk = 0; kk < 2; ++kk) {
            const int slot = 4 * kk + q;
            bh8 af[4], bfv[4];
#pragma unroll
            for (int i = 0; i < 4; ++i) {
                int row = wm + i * 16 + ln;
                af[i] = *(const bh8*)&As[row * 64 + ((slot ^ (row & 7)) * 8)];
            }
#pragma unroll
            for (int j = 0; j < 4; ++j) {
                int row = wn + j * 16 + ln;
                bfv[j] = *(const bh8*)&Bs[row * 64 + ((slot ^ (row & 7)) * 8)];
            }
#pragma unroll
            for (int i = 0; i < 4; ++i)
#pragma unroll
                for (int j = 0; j < 4; ++j)
                    acc[i][j] = __builtin_amdgcn_mfma_f32_16x16x32_bf16(af[i], bfv[j], acc[i][j], 0, 0, 0);
        }
    }

    u16* qb = qkv + (size_t)b * NO_ * HW_;
#pragma unroll
    for (int i = 0; i < 4; ++i) {
#pragma unroll
        for (int r = 0; r < 4; ++r) {
            int o = m0 + wm + i * 16 + q * 4 + r;
            float bia = (o < 64) ? bq[o] : (o < 128) ? bk[o - 64] : bv[o - 128];
#pragma unroll
            for (int j = 0; j < 4; ++j) {
                int s = n0 + wn + j * 16 + ln;
                qb[(size_t)o * HW_ + s] = f2bf(acc[i][j][r] + bia);
            }
        }
    }
}

// ---------------- k_attn: fused scores + softmax + apply ----------------
// grid (4 hs, 8 head, 16 b), 512 threads (8 waves).
// Scores: S[d][e] = sum_l Q[d][l] K[e][l], l<512; element (d,l) of Q lives at
// qbase + (l>>6)*HW + (l&63)*64 + d.  Staged per 64-l macro-step as an LDS
// transpose (pitch 72).  Waves w&3 = m-tile; w>>2 duplicates (redundant).
// Softmax rows in registers (shfl_xor over 16-lane groups), P -> LDS bf16.
// Apply: D[a][w'] = sum_e V[a][h*64+e] * P[w'][e]; V fragments straight from
// global with 1-deep register prefetch, P fragments hoisted from LDS once.
__global__ __launch_bounds__(512) void k_attn(
    const u16* __restrict__ qkv, u16* __restrict__ Xb16)
{
    __shared__ u16 Qs[64 * 72];
    __shared__ u16 Ks[64 * 72];
    __shared__ u16 Ps[64 * 72];
    const int t = threadIdx.x;
    const int lane = t & 63, w = t >> 6;
    const int q = lane >> 4, ln = lane & 15;
    const int hbase = blockIdx.x * 16, head = blockIdx.y, b = blockIdx.z;
    const u16* qbase = qkv + ((size_t)b * NO_ + 8 * head) * HW_;
    const u16* kbase = qkv + ((size_t)b * NO_ + 64 + 8 * head) * HW_;
    const u16* Vg    = qkv + ((size_t)b * NO_ + 128 + 64 * head) * HW_;
    u16* ob = Xb16 + ((size_t)b * C_ + head) * HW_;

    const int m0 = (w & 3) * 16;       // scores m-tile / apply a-tile
    const int sl = t & 63;             // staging: l_lo
    const int sg = t >> 6;             // staging: d-group (8 d's per thread)

    // ---- scores: S = Q K^T over K=512, 8 macro-steps of 64 ----
    f32x4 acc[4];
#pragma unroll
    for (int j = 0; j < 4; ++j) acc[j] = (f32x4){0.f, 0.f, 0.f, 0.f};

    for (int c0 = 0; c0 < 8; ++c0) {
        __syncthreads();
        bh8 qv = *(const bh8*)(qbase + (size_t)c0 * HW_ + sl * 64 + sg * 8);
        bh8 kv = *(const bh8*)(kbase + (size_t)c0 * HW_ + sl * 64 + sg * 8);
#pragma unroll
        for (int i = 0; i < 8; ++i) {
            Qs[(sg * 8 + i) * 72 + sl] = (u16)qv[i];
            Ks[(sg * 8 + i) * 72 + sl] = (u16)kv[i];
        }
        __syncthreads();
        bh8 aq[2], bk_[4][2];
#pragma unroll
        for (int ks = 0; ks < 2; ++ks)
            aq[ks] = *(const bh8*)&Qs[(m0 + ln) * 72 + ks * 32 + q * 8];
#pragma unroll
        for (int j = 0; j < 4; ++j)
#pragma unroll
            for (int ks = 0; ks < 2; ++ks)
                bk_[j][ks] = *(const bh8*)&Ks[(j * 16 + ln) * 72 + ks * 32 + q * 8];
#pragma unroll
        for (int ks = 0; ks < 2; ++ks)
#pragma unroll
            for (int j = 0; j < 4; ++j)
                acc[j] = __builtin_amdgcn_mfma_f32_16x16x32_bf16(aq[ks], bk_[j][ks], acc[j], 0, 0, 0);
    }

    // ---- softmax over e (scale 1/sqrt(64) = 0.125), P -> LDS bf16 ----
#pragma unroll
    for (int r = 0; r < 4; ++r) {
        float pv[4];
        float mx = -1e30f;
#pragma unroll
        for (int j = 0; j < 4; ++j) {
            pv[j] = acc[j][r] * 0.125f;
            mx = fmaxf(mx, pv[j]);
        }
#pragma unroll
        for (int m = 1; m < 16; m <<= 1) mx = fmaxf(mx, __shfl_xor(mx, m));
        float ssum = 0.f;
#pragma unroll
        for (int j = 0; j < 4; ++j) { pv[j] = __expf(pv[j] - mx); ssum += pv[j]; }
#pragma unroll
        for (int m = 1; m < 16; m <<= 1) ssum += __shfl_xor(ssum, m);
        float inv = 1.f / ssum;
        if (w < 4) {
#pragma unroll
            for (int j = 0; j < 4; ++j)
                Ps[(m0 + q * 4 + r) * 72 + j * 16 + ln] = f2bf(pv[j] * inv);
        }
    }
    __syncthreads();

    // ---- apply: D[a][w'] = sum_e V[a][h*64+e] P[w'][e], 8 h per wave ----
    const int a0 = m0;
    const int h0 = hbase + (w >> 2) * 8;
    bh8 pb[4][2];
#pragma unroll
    for (int j = 0; j < 4; ++j)
#pragma unroll
        for (int ks = 0; ks < 2; ++ks)
            pb[j][ks] = *(const bh8*)&Ps[(j * 16 + ln) * 72 + ks * 32 + q * 8];

    const u16* vrow = Vg + (size_t)(a0 + ln) * HW_;
    bh8 vf0[2], vf1[2];
#pragma unroll
    for (int ks = 0; ks < 2; ++ks)
        vf0[ks] = *(const bh8*)(vrow + h0 * 64 + ks * 32 + q * 8);
#pragma unroll
    for (int hi = 0; hi < 8; ++hi) {
        const int h = h0 + hi;
        if (hi < 7) {
#pragma unroll
            for (int ks = 0; ks < 2; ++ks)
                vf1[ks] = *(const bh8*)(vrow + (h + 1) * 64 + ks * 32 + q * 8);
        }
        f32x4 a2[4];
#pragma unroll
        for (int j = 0; j < 4; ++j) a2[j] = (f32x4){0.f, 0.f, 0.f, 0.f};
#pragma unroll
        for (int ks = 0; ks < 2; ++ks)
#pragma unroll
            for (int j = 0; j < 4; ++j)
                a2[j] = __builtin_amdgcn_mfma_f32_16x16x32_bf16(vf0[ks], pb[j][ks], a2[j], 0, 0, 0);

        // X layout: channel c = a*8 + head, spatial h*64+w'.
#pragma unroll
        for (int r = 0; r < 4; ++r) {
            int a = a0 + q * 4 + r;
            u16* orow = ob + (size_t)a * 8 * HW_ + h * 64;
#pragma unroll
            for (int j = 0; j < 4; ++j) orow[j * 16 + ln] = f2bf(a2[j][r]);
        }
#pragma unroll
        for (int ks = 0; ks < 2; ++ks) vf0[ks] = vf1[ks];
    }
}

// ---------------- k_out (MFMA): Y = Xb16 @ Wo_b16^T + bo, fp32 out ----------------
// A = Xb16[65536][512] ([m][k]), B = Wo_b16[512][512] ([n][k]). Tile 128x128, BK=32.
__global__ __launch_bounds__(256) void k_out(
    const u16* __restrict__ Xg, const u16* __restrict__ Wob,
    const float* __restrict__ bo, float* __restrict__ Y)
{
    __shared__ u16 As[128 * 32];
    __shared__ u16 Bs[128 * 32];
    const int t = threadIdx.x;
    const int lane = t & 63, w = t >> 6;
    const int q = lane >> 4, ln = lane & 15;
    const int n0 = blockIdx.x * 128;
    const size_t r0 = (size_t)blockIdx.y * 128;
    const int wm = (w >> 1) * 64, wn = (w & 1) * 64;
    const int srow = lane >> 2, scol = (lane & 3) * 8;

    f32x4 acc[4][4];
#pragma unroll
    for (int i = 0; i < 4; ++i)
#pragma unroll
        for (int j = 0; j < 4; ++j) acc[i][j] = (f32x4){0.f, 0.f, 0.f, 0.f};

    for (int k0 = 0; k0 < C_; k0 += 32) {
        __syncthreads();
#pragma unroll
        for (int i = 0; i < 2; ++i) {
            int rowblk = (i * 4 + w) * 16;
            gl2lds(Xg  + (r0 + rowblk + srow) * C_ + k0 + scol, &As[rowblk * 32]);
            gl2lds(Wob + (size_t)(n0 + rowblk + srow) * C_ + k0 + scol, &Bs[rowblk * 32]);
        }
        __syncthreads();
        bh8 af[4], bfv[4];
#pragma unroll
        for (int i = 0; i < 4; ++i) af[i]  = *(const bh8*)&As[(wm + i * 16 + ln) * 32 + q * 8];
#pragma unroll
        for (int j = 0; j < 4; ++j) bfv[j] = *(const bh8*)&Bs[(wn + j * 16 + ln) * 32 + q * 8];
#pragma unroll
        for (int i = 0; i < 4; ++i)
#pragma unroll
            for (int j = 0; j < 4; ++j)
                acc[i][j] = __builtin_amdgcn_mfma_f32_16x16x32_bf16(af[i], bfv[j], acc[i][j], 0, 0, 0);
    }

#pragma unroll
    for (int i = 0; i < 4; ++i) {
#pragma unroll
        for (int r = 0; r < 4; ++r) {
            size_t row = r0 + wm + i * 16 + q * 4 + r;
#pragma unroll
            for (int j = 0; j < 4; ++j) {
                int col = n0 + wn + j * 16 + ln;
                Y[row * C_ + col] = acc[i][j][r] + bo[col];
            }
        }
    }
}

extern "C" void kernel_launch(void* const* d_in, const int* in_sizes, int n_in,
                              void* d_out, int out_size, void* d_ws, size_t ws_size,
                              hipStream_t stream)
{
    const float* x  = (const float*)d_in[0];
    const float* Wq = (const float*)d_in[1];
    const float* bq = (const float*)d_in[2];
    const float* Wk = (const float*)d_in[3];
    const float* bk = (const float*)d_in[4];
    const float* Wv = (const float*)d_in[5];
    const float* bv = (const float*)d_in[6];
    const float* Wo = (const float*)d_in[7];
    const float* bo = (const float*)d_in[8];

    char* ws = (char*)d_ws;
    u16*   Xb16 = (u16*)ws;                              // [0, 64 MiB)
    u16*   Wcat = (u16*)(ws + 67108864 + 2097152);       // 655,360 B
    u16*   Wob  = (u16*)(ws + 67108864 + 2097152 + 655360); // 524,288 B
    u16*   qkv  = (u16*)d_out;                           // 80 MiB scratch in d_out
    float* Y    = (float*)d_out;

    k_wcvt <<<dim3((NO_ * C_ + C_ * C_ + 255) / 256), 256, 0, stream>>>(Wq, Wk, Wv, Wo, Wcat, Wob);
    k_proj <<<dim3(HW_ / 128, NO_ / 128, B_), 256, 0, stream>>>(Wcat, x, bq, bk, bv, qkv);
    k_attn <<<dim3(4, 8, B_), 512, 0, stream>>>(qkv, Xb16);
    k_out  <<<dim3(C_ / 128, (B_ * HW_) / 128), 256, 0, stream>>>(Xb16, Wob, bo, Y);
}